// Round 4
// baseline (274.483 us; speedup 1.0000x reference)
//
#include <hip/hip_runtime.h>

// rosa_4bit_layer: causal linear attention with per-head 4x4 state.
//   S_t = S_{t-1} + k_t v_t^T ;  o_t = q_t^T S_t ;  out = o * emb
// Shapes: x{q,k,v}: (B=4, T=4096, C=512) fp32, emb: (1,1,512) fp32.
// H = 128 heads, head_dim = 4 (contiguous 4-float groups in C).
//
// R3 post-mortem: all three kernels < 40 us, but the timed window carries
// ~40-80 us of harness workspace-poison fills plus two dispatch drains and
// a cold k,v re-read. R4: ONE dispatch — decoupled-lookback single-pass
// scan (rocPRIM-style):
//   phase 1: per-chunk aggregate A = sum_t k_t v_t^T        (k,v read once)
//   phase 2: lookback over predecessors' published aggregates/prefixes
//   phase 3: publish inclusive prefix (unblocks successors ASAP)
//   phase 4: replay chunk from exclusive prefix (k,v now L2/L3-hot), write.
// Dispatch order is UNDEFINED on CDNA -> blocks take a logical index from
// an atomic ticket, so a block only spins on logically-earlier blocks that
// are already executing => no deadlock independent of residency/order.
// All cross-block payload traffic uses agent-scope atomics (coherence
// point), sidestepping per-XCD L2 non-coherence.
//
// d_ws layout: [0,4KiB) flags[NBLK], [4KiB) ticket, [8KiB) agg (8 MiB),
// then pref (8 MiB). flags+ticket zeroed by a hipMemsetAsync graph node.

constexpr int B  = 4;
constexpr int T  = 4096;
constexpr int C  = 512;
constexpr int CT = 16;        // timesteps per chunk
constexpr int NC = T / CT;    // 256 chunks per sequence
constexpr int NBLK  = B * NC; // 1024 blocks = full residency at 4/CU
constexpr int STATE = 2048;   // floats of state per chunk (128 heads * 16)
constexpr int LOOKB = 4;      // lookback batch depth (keeps VGPR <= 64)

#define AGENT_LD(p)    __hip_atomic_load((p),  __ATOMIC_RELAXED, __HIP_MEMORY_SCOPE_AGENT)
#define AGENT_ST(p, x) __hip_atomic_store((p), (x), __ATOMIC_RELAXED, __HIP_MEMORY_SCOPE_AGENT)

__global__ __launch_bounds__(512, 8) void k_fused(
    const float* __restrict__ q, const float* __restrict__ k,
    const float* __restrict__ v, const float* __restrict__ emb,
    int* __restrict__ flags, int* __restrict__ ticket,
    float* __restrict__ agg, float* __restrict__ pref,
    float* __restrict__ out)
{
  const int tid = threadIdx.x;           // 0..511
  __shared__ int s_lb;
  if (tid == 0) s_lb = atomicAdd(ticket, 1);
  __syncthreads();
  const int lb = s_lb;                   // logical block: b*NC + c (exec-ordered)
  const int b  = lb >> 8;                // / NC
  const int c  = lb & (NC - 1);
  const int h  = tid >> 2;
  const int e  = tid & 3;

  const size_t base = ((size_t)b * T + c * CT) * (size_t)C + (h << 2);
  const float* kb = k + base;
  const float* vb = v + base + e;

  // ---- phase 1: local chunk aggregate ----
  float A0 = 0.f, A1 = 0.f, A2 = 0.f, A3 = 0.f;
#pragma unroll 8
  for (int t = 0; t < CT; ++t) {
    const float4 k4 = *reinterpret_cast<const float4*>(kb + (size_t)t * C);
    const float  ve = vb[(size_t)t * C];
    A0 += k4.x * ve; A1 += k4.y * ve; A2 += k4.z * ve; A3 += k4.w * ve;
  }
  // publish aggregate (component-major: each store wave-coalesced)
  {
    float* a = agg + (size_t)lb * STATE;
    AGENT_ST(a +         tid, A0);
    AGENT_ST(a +  512 +  tid, A1);
    AGENT_ST(a + 1024 +  tid, A2);
    AGENT_ST(a + 1536 +  tid, A3);
  }
  __syncthreads();                       // drains vmcnt(0): all payload stores done
  if (tid == 0)
    __hip_atomic_store(&flags[lb], 1, __ATOMIC_RELEASE, __HIP_MEMORY_SCOPE_AGENT);

  // ---- phase 2: decoupled lookback -> exclusive prefix E ----
  float E0 = 0.f, E1 = 0.f, E2 = 0.f, E3 = 0.f;
  if (c > 0) {
    const int lo = lb - c;               // logical id of this sequence's chunk 0
    int look = lb - 1;
    bool done = false;
    while (!done) {
      const int cnt = (look - lo + 1 < LOOKB) ? (look - lo + 1) : LOOKB;
      int fl[LOOKB];
#pragma unroll
      for (int i = 0; i < LOOKB; ++i)
        if (i < cnt) fl[i] = AGENT_LD(&flags[look - i]);
#pragma unroll
      for (int i = 0; i < LOOKB; ++i)
        if (i < cnt)
          while (fl[i] == 0) {           // rare: predecessor not yet published
            __builtin_amdgcn_s_sleep(1);
            fl[i] = AGENT_LD(&flags[look - i]);
          }
      // speculatively issue all payload loads (independent, in flight together)
      float p0[LOOKB], p1[LOOKB], p2[LOOKB], p3[LOOKB];
#pragma unroll
      for (int i = 0; i < LOOKB; ++i)
        if (i < cnt) {
          const float* src =
              (fl[i] == 2 ? pref : agg) + (size_t)(look - i) * STATE + tid;
          p0[i] = AGENT_LD(src);
          p1[i] = AGENT_LD(src +  512);
          p2[i] = AGENT_LD(src + 1024);
          p3[i] = AGENT_LD(src + 1536);
        }
#pragma unroll
      for (int i = 0; i < LOOKB; ++i) {
        if (i < cnt && !done) {
          E0 += p0[i]; E1 += p1[i]; E2 += p2[i]; E3 += p3[i];
          if (fl[i] == 2) done = true;   // absorbed an inclusive prefix: stop
        }
      }
      if (!done) {
        if (look - cnt + 1 == lo) done = true;  // consumed through chunk 0
        look -= cnt;
      }
    }
  }

  // ---- phase 3: publish inclusive prefix ASAP (unblocks successors) ----
  {
    float* p = pref + (size_t)lb * STATE;
    AGENT_ST(p +         tid, E0 + A0);
    AGENT_ST(p +  512 +  tid, E1 + A1);
    AGENT_ST(p + 1024 +  tid, E2 + A2);
    AGENT_ST(p + 1536 +  tid, E3 + A3);
  }
  __syncthreads();
  if (tid == 0)
    __hip_atomic_store(&flags[lb], 2, __ATOMIC_RELEASE, __HIP_MEMORY_SCOPE_AGENT);

  // ---- phase 4: replay chunk from exclusive prefix, write out ----
  const float* qb = q + base;
  float*       ob = out + base + e;
  const float embv = emb[tid];           // (h<<2)+e == tid, tid spans C
  float S0 = E0, S1 = E1, S2 = E2, S3 = E3;
#pragma unroll 4
  for (int t = 0; t < CT; ++t) {
    const float4 k4 = *reinterpret_cast<const float4*>(kb + (size_t)t * C);
    const float4 q4 = *reinterpret_cast<const float4*>(qb + (size_t)t * C);
    const float  ve = vb[(size_t)t * C];
    S0 += k4.x * ve; S1 += k4.y * ve; S2 += k4.z * ve; S3 += k4.w * ve;
    ob[(size_t)t * C] = (q4.x * S0 + q4.y * S1 + q4.z * S2 + q4.w * S3) * embv;
  }
}

extern "C" void kernel_launch(void* const* d_in, const int* in_sizes, int n_in,
                              void* d_out, int out_size, void* d_ws, size_t ws_size,
                              hipStream_t stream) {
  const float* xq  = (const float*)d_in[0];
  const float* xk  = (const float*)d_in[1];
  const float* xv  = (const float*)d_in[2];
  const float* emb = (const float*)d_in[3];
  float* out = (float*)d_out;

  int*   flags  = (int*)d_ws;                                   // 4 KiB
  int*   ticket = (int*)((char*)d_ws + 4096);                   // 4 B
  float* agg    = (float*)((char*)d_ws + 8192);                 // 8 MiB
  float* pref   = agg + (size_t)NBLK * STATE;                   // 8 MiB

  hipMemsetAsync(d_ws, 0, 8192, stream);   // zero flags + ticket (graph node)
  k_fused<<<NBLK, 512, 0, stream>>>(xq, xk, xv, emb, flags, ticket,
                                    agg, pref, out);
}

// Round 6
// 173.645 us; speedup vs baseline: 1.5807x; 1.5807x over previous
//
#include <hip/hip_runtime.h>

// rosa_4bit_layer: causal linear attention with per-head 4x4 state.
//   S_t = S_{t-1} + k_t v_t^T ;  o_t = q_t^T S_t ;  out = o * emb
// Shapes: x{q,k,v}: (B=4, T=4096, C=512) fp32, emb: (1,1,512) fp32.
// H = 128 heads, head_dim = 4 (contiguous 4-float groups in C).
//
// R4 post-mortem: decoupled lookback = 182 us (agent-scope payloads bypass
// the per-XCD L2 -> ~1 GB of uncached traffic + 256-deep serial chain).
// R4 also calibrated fixed harness overhead at ~90 us, leaving ~57 us of
// controllable kernel+gap time in the R3 3-dispatch version.
// R5 bench was an infra failure (container died twice); this is the same
// kernel resubmitted.
//
// R5: TWO dispatches, hierarchical scan, no cross-block sync.
// Partition: (b, head-group hg of 16 heads, chunk c of CT=128 timesteps).
// 4*8*32 = 1024 blocks x 512 threads (8 sub-chunks x 64 lanes) = 100% occ.
//   K1: per-chunk aggregate via LDS reduce of 8 sub-chunk aggregates
//       -> only 32 aggregates per (b,hg) column, 1 MiB total in d_ws.
//   K2: each wave gathers <=4 predecessor chunk aggregates (8 waves cover
//       <=31), LDS-combines them with the in-block sub-chunk scan, then
//       replays its 16 timesteps and writes out. No scan dispatch at all.
// Thread (h,e) owns column e of head h's 4x4 state: S[d][e], d=0..3.

constexpr int B   = 4;
constexpr int T   = 4096;
constexpr int C   = 512;
constexpr int HG  = 8;          // head groups (16 heads = 64 floats each)
constexpr int NC  = 32;         // chunks per sequence
constexpr int CT  = T / NC;     // 128 timesteps per chunk
constexpr int SUB = 8;          // sub-chunks per block (= waves)
constexpr int TS  = CT / SUB;   // 16 timesteps per thread
constexpr int NBLK = B * HG * NC;  // 1024
// agg: one float4 per (block, lane): NBLK*64*16B = 1 MiB in d_ws.

__device__ __forceinline__ void fma4(float4& a, const float4& k4, float ve) {
  a.x += k4.x * ve; a.y += k4.y * ve; a.z += k4.z * ve; a.w += k4.w * ve;
}
__device__ __forceinline__ void add4(float4& a, const float4& b) {
  a.x += b.x; a.y += b.y; a.z += b.z; a.w += b.w;
}

__global__ __launch_bounds__(512, 8) void k_partial(const float* __restrict__ k,
                                                    const float* __restrict__ v,
                                                    float4* __restrict__ agg) {
  const int bc   = blockIdx.x;          // ((b*HG+hg)*NC + c)
  const int b    = bc >> 8;
  const int hg   = (bc >> 5) & 7;
  const int c    = bc & 31;
  const int tid  = threadIdx.x;
  const int sg   = tid >> 6;            // sub-chunk == wave index (uniform)
  const int lane = tid & 63;
  const int h    = lane >> 2;
  const int e    = lane & 3;

  const int t0 = c * CT + sg * TS;
  const size_t base = ((size_t)b * T + t0) * (size_t)C + hg * 64 + (h << 2);
  const float* kb = k + base;
  const float* vb = v + base + e;

  float4 A = {0.f, 0.f, 0.f, 0.f};
#pragma unroll
  for (int t = 0; t < TS; ++t) {
    const float4 k4 = *reinterpret_cast<const float4*>(kb + (size_t)t * C);
    fma4(A, k4, vb[(size_t)t * C]);
  }

  __shared__ float4 lds[SUB][64];
  lds[sg][lane] = A;
  __syncthreads();
  if (sg == 0) {
    float4 s = lds[0][lane];
#pragma unroll
    for (int g = 1; g < SUB; ++g) add4(s, lds[g][lane]);
    agg[(size_t)bc * 64 + lane] = s;    // 1 KiB per block, wave-coalesced
  }
}

__global__ __launch_bounds__(512, 8) void k_out(const float* __restrict__ q,
                                                const float* __restrict__ k,
                                                const float* __restrict__ v,
                                                const float* __restrict__ emb,
                                                const float4* __restrict__ agg,
                                                float* __restrict__ out) {
  const int bc   = blockIdx.x;
  const int b    = bc >> 8;
  const int hg   = (bc >> 5) & 7;
  const int c    = bc & 31;
  const int tid  = threadIdx.x;
  const int sg   = tid >> 6;            // wave-uniform
  const int lane = tid & 63;
  const int h    = lane >> 2;
  const int e    = lane & 3;

  // ---- gather predecessor chunk aggregates, split across the 8 waves ----
  // wave sg takes cc = sg, sg+8, sg+16, sg+24 (< c): <=4 independent
  // batched float4 loads from the 1 MiB L2-hot agg buffer.
  const size_t col = ((size_t)bc - c) * 64 + lane;  // column base (cc = 0)
  float4 G = {0.f, 0.f, 0.f, 0.f};
#pragma unroll
  for (int i = 0; i < 4; ++i) {
    const int cc = sg + i * 8;
    if (cc < c) {
      const float4 a = agg[col + (size_t)cc * 64];
      add4(G, a);
    }
  }

  // ---- local sub-chunk aggregate (phase A) ----
  const int t0 = c * CT + sg * TS;
  const size_t base = ((size_t)b * T + t0) * (size_t)C + hg * 64 + (h << 2);
  const float* kb = k + base;
  const float* vb = v + base + e;

  float4 A = {0.f, 0.f, 0.f, 0.f};
#pragma unroll
  for (int t = 0; t < TS; ++t) {
    const float4 k4 = *reinterpret_cast<const float4*>(kb + (size_t)t * C);
    fma4(A, k4, vb[(size_t)t * C]);
  }

  // ---- combine: block-start prefix + exclusive in-block sub-chunk scan ----
  __shared__ float4 lds_g[SUB][64];
  __shared__ float4 lds_s[SUB][64];
  lds_g[sg][lane] = G;
  lds_s[sg][lane] = A;
  __syncthreads();

  float4 S = {0.f, 0.f, 0.f, 0.f};
#pragma unroll
  for (int g = 0; g < SUB; ++g) add4(S, lds_g[g][lane]);   // global prefix
#pragma unroll
  for (int g = 0; g < SUB - 1; ++g)
    if (g < sg) add4(S, lds_s[g][lane]);                   // uniform: no div

  // ---- replay (phase D): k,v re-reads are L1/L2-hot ----
  const float* qb = q + base;
  float*       ob = out + base + e;
  const float embv = emb[hg * 64 + (h << 2) + e];
#pragma unroll
  for (int t = 0; t < TS; ++t) {
    const float4 k4 = *reinterpret_cast<const float4*>(kb + (size_t)t * C);
    const float4 q4 = *reinterpret_cast<const float4*>(qb + (size_t)t * C);
    fma4(S, k4, vb[(size_t)t * C]);
    const float o = q4.x * S.x + q4.y * S.y + q4.z * S.z + q4.w * S.w;
    ob[(size_t)t * C] = o * embv;
  }
}

extern "C" void kernel_launch(void* const* d_in, const int* in_sizes, int n_in,
                              void* d_out, int out_size, void* d_ws, size_t ws_size,
                              hipStream_t stream) {
  const float* xq  = (const float*)d_in[0];
  const float* xk  = (const float*)d_in[1];
  const float* xv  = (const float*)d_in[2];
  const float* emb = (const float*)d_in[3];
  float*  out = (float*)d_out;
  float4* agg = (float4*)d_ws;   // 1 MiB

  k_partial<<<NBLK, 512, 0, stream>>>(xk, xv, agg);
  k_out<<<NBLK, 512, 0, stream>>>(xq, xk, xv, emb, agg, out);
}